// Round 4
// baseline (1148.204 us; speedup 1.0000x reference)
//
#include <hip/hip_runtime.h>

// PhotonicNetworkGPU on MI355X — round 4: LDS-pipe de-bottlenecking.
// Block = 1024 thr = 16 waves = 8 rowgroups x 2 colgroups; mfma 32x32x16.
// Field tile in LDS bf16, col-major fldT[c][s], c = 2*m_local + comp
// (re/im of the same m in adjacent lanes -> epilogue pairing via shfl_xor(1)).
// conn is repacked FRAGMENT-MAJOR bf16 in d_ws: chunk(rg,kk,lane)=16B, so an
// A-fragment load is one coalesced 1KB wave load (L1/L2-resident).
// Staging transposes at the GLOBAL level: thread(c, s-quad) gathers 4 scalar
// (coalesced across lanes) loads and writes ONE aligned ds_write_b64 -> the
// 16 scalar conflicted b16 writes of round 3 are gone.
// gain/bias/0.95*ww live in per-lane registers (rows fixed per lane).

#define NB 32
#define NS 256
#define NW 64
#define NM 64
#define PLANE (NB * NS * NW * NM)
#define PITCH 264   // bf16 col pitch: 528 B -> b128/b64 2-way at worst (free)
#define PM 36       // f32 pitch for the output staging view
#define TILES 8

typedef short bfrag __attribute__((ext_vector_type(8)));
typedef short bfx4  __attribute__((ext_vector_type(4)));
typedef float accv  __attribute__((ext_vector_type(16)));
typedef float fx4   __attribute__((ext_vector_type(4)));

__device__ __forceinline__ short f2bf(float x) {   // RNE f32 -> bf16
    union { float f; unsigned u; } v; v.f = x;
    unsigned r = (v.u + 0x7fffu + ((v.u >> 16) & 1u)) >> 16;
    return (short)r;
}
__device__ __forceinline__ float bf2f(short s) {
    union { unsigned u; float f; } v; v.u = ((unsigned)(unsigned short)s) << 16;
    return v.f;
}
__device__ __forceinline__ unsigned pk2(float a, float b) {
    return (unsigned)(unsigned short)f2bf(a) | ((unsigned)(unsigned short)f2bf(b) << 16);
}

// Repack conn f32[256][256] -> bf16 fragment-major:
// chunk index ((rg*16 + kk)*64 + lane), 8 bf16 each:
//   row = rg*32 + (lane&31), k = (lane>>5)*8 + kk*16 + e
__global__ __launch_bounds__(256)
void conn_pack(const float* __restrict__ c, short* __restrict__ o) {
    const int i4   = (blockIdx.x * 256 + threadIdx.x) * 4;   // 0..65532
    const int e    = i4 & 7;                                  // 0 or 4
    const int lane = (i4 >> 3) & 63;
    const int kk   = (i4 >> 9) & 15;
    const int rg   = i4 >> 13;
    const int row  = rg * 32 + (lane & 31);
    const int col  = (lane >> 5) * 8 + kk * 16 + e;
    const float4 v = *reinterpret_cast<const float4*>(c + row * NS + col);
    *reinterpret_cast<uint2*>(o + i4) = make_uint2(pk2(v.x, v.y), pk2(v.z, v.w));
}

__global__ __launch_bounds__(1024, 4)
void photonic_mfma(const float* __restrict__ fr, const float* __restrict__ fi,
                   const short* __restrict__ cb, const float* __restrict__ gain,
                   const float* __restrict__ bias, const float* __restrict__ ww,
                   const float* __restrict__ dshape, float* __restrict__ out)
{
    __shared__ __align__(16) float fb[NS * PM];   // 36,864 B; bf16 view fldT
    short* const fldT = (short*)fb;

    const int t    = threadIdx.x;
    const int bid  = blockIdx.x;
    const int w    = bid >> 3;         // 0..63
    const int grp  = bid & 7;          // 0..7

    const int lane = t & 63;
    const int wv   = t >> 6;           // 0..15
    const int rg   = wv >> 1;          // 0..7  rowgroup
    const int cg   = wv & 1;           // 0..1  colgroup
    const int l31  = lane & 31;
    const int half = lane >> 5;
    const int rowb = rg * 32;

    const int c_mine = cg * 32 + l31;                       // my B/C/D column
    const int comp   = c_mine & 1;                          // 0=re 1=im
    const int m_half = ((c_mine >> 1) & 15) | ((c_mine >> 5) << 4);

    // ---- per-lane row constants in registers (rows fixed for the session) --
    float g_r[16], b_r[16], zz[16];
    #pragma unroll
    for (int j = 0; j < 16; ++j) {
        const int row = rowb + (j & 3) + 8 * (j >> 2) + 4 * half;
        g_r[j] = gain[row];
        b_r[j] = bias[row];
        zz[j]  = 0.95f * ww[row * NW + w];
    }
    const float th  = 0.1f * dshape[w];
    const float cpr = cosf(th);
    const float cpi = sinf(th);

    // ---- staging role: thread = (col sc, s-group sgrp) ----
    const int sc    = t & 63;
    const int sgrp  = t >> 6;          // 0..15
    const int scomp = sc & 1;
    const int sm    = ((sc >> 1) & 15) | ((sc >> 5) << 4);
    const float* const sbase = scomp ? fi : fr;

    // ---- prefetch tile 0 ----
    float pre[16];
    {
        const int td = grp * TILES;
        const int b0 = td >> 1, h0 = td & 1;
        #pragma unroll
        for (int pass = 0; pass < 4; ++pass) {
            const int sq = pass * 16 + sgrp;
            #pragma unroll
            for (int k = 0; k < 4; ++k) {
                const int s = sq * 4 + k;
                const int g = ((b0 * NS + s) * NW + w) * NM + h0 * 32 + sm;
                pre[pass * 4 + k] = __builtin_nontemporal_load(sbase + g);
            }
        }
    }

    const short* const aP = cb + rg * 8192 + lane * 8;          // A chunks
    const short* const bP = &fldT[c_mine * PITCH + half * 8];   // B column

    for (int tile = 0; tile < TILES; ++tile) {
        const int td = grp * TILES + tile;
        const int b  = td >> 1;
        const int h  = td & 1;

        __syncthreads();   // fb/fldT free (prev tile fully stored)

        // ---- staging: 4 aligned b64 writes per thread ----
        #pragma unroll
        for (int pass = 0; pass < 4; ++pass) {
            const int sq = pass * 16 + sgrp;
            *reinterpret_cast<uint2*>(&fldT[sc * PITCH + sq * 4]) =
                make_uint2(pk2(pre[pass * 4 + 0], pre[pass * 4 + 1]),
                           pk2(pre[pass * 4 + 2], pre[pass * 4 + 3]));
        }

        // ---- issue next tile's gather loads ----
        if (tile + 1 < TILES) {
            const int td2 = grp * TILES + tile + 1;
            const int b2 = td2 >> 1, h2 = td2 & 1;
            #pragma unroll
            for (int pass = 0; pass < 4; ++pass) {
                const int sq = pass * 16 + sgrp;
                #pragma unroll
                for (int k = 0; k < 4; ++k) {
                    const int s = sq * 4 + k;
                    const int g = ((b2 * NS + s) * NW + w) * NM + h2 * 32 + sm;
                    pre[pass * 4 + k] = __builtin_nontemporal_load(sbase + g);
                }
            }
        }

        __syncthreads();

        // ---- fp32 state init from staged bf16 ----
        float st[16];
        #pragma unroll
        for (int q2 = 0; q2 < 4; ++q2) {
            const int srow = rowb + 8 * q2 + 4 * half;
            const bfx4 v = *reinterpret_cast<const bfx4*>(&fldT[c_mine * PITCH + srow]);
            #pragma unroll
            for (int j = 0; j < 4; ++j) st[q2 * 4 + j] = bf2f(v[j]);
        }

        for (int step = 0; step < 4; ++step) {
            if (step > 0) __syncthreads();   // prev epilogue writes visible

            accv acc;
            #pragma unroll
            for (int j = 0; j < 16; ++j) acc[j] = 0.0f;

            #pragma unroll
            for (int kk = 0; kk < 16; ++kk) {
                const bfrag A  = *reinterpret_cast<const bfrag*>(aP + kk * 512);
                const bfrag Bv = *reinterpret_cast<const bfrag*>(bP + kk * 16);
                acc = __builtin_amdgcn_mfma_f32_32x32x16_bf16(A, Bv, acc, 0, 0, 0);
            }

            __syncthreads();   // all B reads done

            if (step < 3) {
                #pragma unroll
                for (int q2 = 0; q2 < 4; ++q2) {
                    const int srow = rowb + 8 * q2 + 4 * half;
                    unsigned short pk[4];
                    #pragma unroll
                    for (int jj = 0; jj < 4; ++jj) {
                        const int j = q2 * 4 + jj;
                        const float v = g_r[j] * (st[j] + acc[j]) + (comp ? 0.0f : b_r[j]);
                        const float p = __shfl_xor(v, 1);
                        float re = comp ? p : v;
                        float im = comp ? v : p;
                        const float inv = 1.0f / (1.0f + 0.5f * (re * re + im * im));
                        re *= inv; im *= inv;
                        const float o = comp ? (re * cpi + im * cpr) * zz[j]
                                             : (re * cpr - im * cpi) * zz[j];
                        st[j] = o;
                        pk[jj] = (unsigned short)f2bf(o);
                    }
                    *reinterpret_cast<uint2*>(&fldT[c_mine * PITCH + srow]) =
                        make_uint2(pk[0] | ((unsigned)pk[1] << 16),
                                   pk[2] | ((unsigned)pk[3] << 16));
                }
            } else {
                #pragma unroll
                for (int j = 0; j < 16; ++j) {
                    const float v = g_r[j] * (st[j] + acc[j]) + (comp ? 0.0f : b_r[j]);
                    const float p = __shfl_xor(v, 1);
                    float re = comp ? p : v;
                    float im = comp ? v : p;
                    const float inv = 1.0f / (1.0f + 0.5f * (re * re + im * im));
                    re *= inv; im *= inv;
                    st[j] = comp ? (re * cpi + im * cpr) * zz[j]
                                 : (re * cpr - im * cpi) * zz[j];
                }
                // ---- re plane: stage f32 in fb, store full-line float4 ----
                if (comp == 0) {
                    #pragma unroll
                    for (int j = 0; j < 16; ++j) {
                        const int row = rowb + (j & 3) + 8 * (j >> 2) + 4 * half;
                        fb[row * PM + m_half] = st[j];
                    }
                }
                __syncthreads();
                #pragma unroll
                for (int it = 0; it < 2; ++it) {
                    const int slot = it * 1024 + t;
                    const int s  = slot >> 3;
                    const int mq = slot & 7;
                    const fx4 v4 = *reinterpret_cast<const fx4*>(&fb[s * PM + mq * 4]);
                    const int gi = ((b * NS + s) * NW + w) * NM + h * 32 + mq * 4;
                    __builtin_nontemporal_store(v4, reinterpret_cast<fx4*>(out + gi));
                }
                __syncthreads();
                // ---- im plane ----
                if (comp == 1) {
                    #pragma unroll
                    for (int j = 0; j < 16; ++j) {
                        const int row = rowb + (j & 3) + 8 * (j >> 2) + 4 * half;
                        fb[row * PM + m_half] = st[j];
                    }
                }
                __syncthreads();
                #pragma unroll
                for (int it = 0; it < 2; ++it) {
                    const int slot = it * 1024 + t;
                    const int s  = slot >> 3;
                    const int mq = slot & 7;
                    const fx4 v4 = *reinterpret_cast<const fx4*>(&fb[s * PM + mq * 4]);
                    const int gi = ((b * NS + s) * NW + w) * NM + h * 32 + mq * 4;
                    __builtin_nontemporal_store(v4, reinterpret_cast<fx4*>(out + PLANE + gi));
                }
            }
        }
    }
}

extern "C" void kernel_launch(void* const* d_in, const int* in_sizes, int n_in,
                              void* d_out, int out_size, void* d_ws, size_t ws_size,
                              hipStream_t stream)
{
    const float* fr  = (const float*)d_in[0];
    const float* fi  = (const float*)d_in[1];
    const float* cn  = (const float*)d_in[2];
    const float* gn  = (const float*)d_in[3];
    const float* bs  = (const float*)d_in[4];
    const float* wwp = (const float*)d_in[5];
    const float* ds  = (const float*)d_in[6];
    float* out = (float*)d_out;
    short* cb  = (short*)d_ws;   // 65536 bf16 = 128 KiB, fragment-major

    hipLaunchKernelGGL(conn_pack, dim3(64), dim3(256), 0, stream, cn, cb);
    hipLaunchKernelGGL(photonic_mfma, dim3(NW * 8), dim3(1024), 0, stream,
                       fr, fi, cb, gn, bs, wwp, ds, out);
}